// Round 3
// baseline (6578.934 us; speedup 1.0000x reference)
//
#include <hip/hip_runtime.h>

// ============================================================================
// ACTP two-layer LSTM rollout, persistent-kernel bf16-MFMA implementation.
//
// R8 change: cut the worst-pass live set to fit the 128-reg budget WITH the
// compiler's ~40-reg scheduling overhead (R7 lesson: nominal accounting runs
// 30-50 regs light; spending freed regs on a[4]/b[8] prefetch (48 regs) was
// self-inflicted spill).
//   Evidence (R7 counters): dur 4224us == hbm_bytes/1.44TB/s exactly; WRITE
//   690MB (output 63MB -> ~630MB scratch stores, 16 dw/thread-step), FETCH
//   5.12GB (~125 dw/thread-step reloads): loop-invariant + loop-carried
//   values spilled once, reloaded every gemm pass, missing L2.
//   Fixes (all register-diet, no structural change):
//    1. Prefetch a[4]->a[2], b[8]->b[4]: -24 regs. A stall-on-L2 gemm
//       (~200cy) beats a scratch-miss pipeline (~900cy/reload).
//    2. Biases un-hoisted: loaded per-pass from L2 (1 dword / 16-29 MFMAs).
//    3. Gate order f->i->g->o: c*=sig(f) in place; tmp=sig(i) lives across
//       ONE pass boundary; c+=tmp*tanh(g); o last. Kills the 16-reg ig
//       held across two boundaries.
//   Worst-pass nominal: c1 16 + c2 16 + tmp 16 + b 16 + a 8 + addr ~12 ~= 85.
//
// Structure:
//  - 1024 blocks x 512 threads (8 waves), 32 batch rows/block, 19 steps.
//  - Wave q=wid: gate-col-tile jt=q (q==7 idle in LSTM gemms). 4 single-gate
//    passes per cell, one f32x16 AGPR accumulator each.
//  - h1/h2 double-buffered in LDS bf16 (32 rows x stride 232), 64KB static.
//    fc1 "out3" aliases dead h1-old.
//  - Weights pre-converted to bf16 fragment-major (frag = 64 lanes x 16B,
//    coalesced 1KB loads), N padded 200->224 (7 jt of 32), K chunks of 16.
//  - fc1/fc2 skipped for context steps 0..8 (outputs unused).
// MFMA v_mfma_f32_32x32x16_bf16 layouts (per cdna4_isa.md):
//   A: m=lane&31, k=8*(lane>>5)+i ; B: n=lane&31, k=8*(lane>>5)+i
//   C/D: col=lane&31, row=(r&3)+8*(r>>2)+4*(lane>>5)
// ============================================================================

typedef short bf16x8 __attribute__((ext_vector_type(8)));
typedef float f32x16 __attribute__((ext_vector_type(16)));

#define NFRAG    1398
#define FRAG_B2  448     // lstm1: 4*7*16 frags
#define FRAG_BF1 1260    // lstm2: 4*7*29 frags
#define FRAG_BF2 1372    // fc1:   7*16 frags ; fc2: 2*13 frags

__device__ __forceinline__ unsigned short f2bf(float f) {
  unsigned int x = __float_as_uint(f);
  x += 0x7fffu + ((x >> 16) & 1u);          // RNE; inputs are finite
  return (unsigned short)(x >> 16);
}
__device__ __forceinline__ float sigf(float x) {
  return __builtin_amdgcn_rcpf(1.f + __expf(-x));   // exp(inf)->inf->rcp->0: safe
}
__device__ __forceinline__ float tanh_f(float x) {
  float e = __expf(2.f * fabsf(x));                 // e>=1, inf handled (t->1)
  float t = 1.f - 2.f * __builtin_amdgcn_rcpf(e + 1.f);
  return copysignf(t, x);
}

// ---------------------------------------------------------------------------
// Prep: fp32 weights -> bf16 fragment-major in d_ws; biases bb = bih + bhh.
// ---------------------------------------------------------------------------
__global__ void actp_prep(
    const float* __restrict__ Wih1, const float* __restrict__ Whh1,
    const float* __restrict__ bih1, const float* __restrict__ bhh1,
    const float* __restrict__ Wih2, const float* __restrict__ Whh2,
    const float* __restrict__ bih2, const float* __restrict__ bhh2,
    const float* __restrict__ W1,   const float* __restrict__ W2,
    unsigned short* __restrict__ ws)
{
  const int bid = blockIdx.x, l = threadIdx.x;
  if (bid >= NFRAG) {                      // bias blocks
    const int idx = (bid - NFRAG) * 64 + l;
    float* bb = (float*)(ws + (size_t)NFRAG * 512);   // bytes NFRAG*1024
    if (idx < 800)        bb[idx] = bih1[idx] + bhh1[idx];
    else if (idx < 1600)  bb[idx] = bih2[idx - 800] + bhh2[idx - 800];
    return;
  }
  const int ncol = l & 31;
  const int kb   = (l >> 5) * 8;
  float v[8];
  if (bid < FRAG_B2) {                     // lstm1: K = [x1(48) | h1(208 pad)]
    int t = bid; const int g = t / 112; t -= g * 112;
    const int jt = t / 16, kc = t % 16;
    const int n = jt * 32 + ncol, row = g * 200 + n;
#pragma unroll
    for (int i = 0; i < 8; ++i) {
      const int k = kc * 16 + kb + i; float val = 0.f;
      if (n < 200) {
        if (kc < 3) val = Wih1[row * 48 + k];
        else { const int kk = k - 48; if (kk < 200) val = Whh1[row * 200 + kk]; }
      }
      v[i] = val;
    }
  } else if (bid < FRAG_BF1) {             // lstm2: K = [h1 208 | tiled 48 | h2 208]
    int t = bid - FRAG_B2; const int g = t / 203; t -= g * 203;
    const int jt = t / 29, kc = t % 29;
    const int n = jt * 32 + ncol, row = g * 200 + n;
#pragma unroll
    for (int i = 0; i < 8; ++i) {
      const int k = kc * 16 + kb + i; float val = 0.f;
      if (n < 200) {
        if (kc < 13)      { if (k < 200) val = Wih2[row * 248 + k]; }
        else if (kc < 16) { val = Wih2[row * 248 + 200 + (k - 208)]; }
        else { const int kk = k - 256; if (kk < 200) val = Whh2[row * 200 + kk]; }
      }
      v[i] = val;
    }
  } else if (bid < FRAG_BF2) {             // fc1: K = [h2 208 | x1 48]
    int t = bid - FRAG_BF1; const int jt = t / 16, kc = t % 16;
    const int n = jt * 32 + ncol;
#pragma unroll
    for (int i = 0; i < 8; ++i) {
      const int k = kc * 16 + kb + i; float val = 0.f;
      if (n < 200) {
        if (kc < 13) { if (k < 200) val = W1[n * 248 + k]; }
        else         val = W1[n * 248 + 200 + (k - 208)];
      }
      v[i] = val;
    }
  } else {                                 // fc2: K = out3(208 pad), N 48->64
    int t = bid - FRAG_BF2; const int jt = t / 13, kc = t % 13;
    const int n = jt * 32 + ncol;
#pragma unroll
    for (int i = 0; i < 8; ++i) {
      const int k = kc * 16 + kb + i; float val = 0.f;
      if (n < 48 && k < 200) val = W2[n * 200 + k];
      v[i] = val;
    }
  }
  bf16x8 o;
#pragma unroll
  for (int i = 0; i < 8; ++i) o[i] = (short)f2bf(v[i]);
  ((bf16x8*)ws)[(size_t)bid * 64 + l] = o;
}

// ---------------------------------------------------------------------------
// Single-gate GEMM. A from LDS (up to 3 segments), B from global
// fragment-major. ONE f32x16 accumulator (AGPR). A 2-deep, B 4-deep
// prefetch (register diet: R8); all rotating indices compile-time.
// ---------------------------------------------------------------------------
template<int KC, int C1, int C2>
__device__ __forceinline__ f32x16 gemm1g(
    const unsigned short* __restrict__ A1, int S1,
    const unsigned short* __restrict__ A2, int S2,
    const unsigned short* __restrict__ A3, int S3,
    const bf16x8* __restrict__ B, int lane)
{
  const int r32 = lane & 31, ao = (lane >> 5) * 8;
#define APTR(kc) ((kc) < C1 ? (A1 + r32 * S1 + (kc) * 16 + ao) \
               : ((kc) < C2 ? (A2 + r32 * S2 + ((kc) - C1) * 16 + ao) \
                            : (A3 + r32 * S3 + ((kc) - C2) * 16 + ao)))
  f32x16 acc;
#pragma unroll
  for (int r = 0; r < 16; ++r) acc[r] = 0.f;
  bf16x8 a[2];
#pragma unroll
  for (int p = 0; p < 2 && p < KC; ++p) a[p] = *(const bf16x8*)APTR(p);
  bf16x8 b[4];
#pragma unroll
  for (int p = 0; p < 4 && p < KC; ++p) b[p] = B[(size_t)p * 64 + lane];
#pragma unroll
  for (int kc = 0; kc < KC; ++kc) {
    acc = __builtin_amdgcn_mfma_f32_32x32x16_bf16(a[kc & 1], b[kc & 3], acc, 0, 0, 0);
    if (kc + 2 < KC) a[kc & 1] = *(const bf16x8*)APTR(kc + 2);
    if (kc + 4 < KC) b[kc & 3] = B[(size_t)(kc + 4) * 64 + lane];
  }
#undef APTR
  return acc;
}

// ---------------------------------------------------------------------------
// Main persistent kernel: 1024 blocks x 512 threads (8 waves), 32 batch rows
// per block. Static 64KB LDS; waves_per_eu(2). 4-pass f->i->g->o cell
// structure; worst-pass arch live set ~85 nominal.
// ---------------------------------------------------------------------------
__global__ __launch_bounds__(512)
__attribute__((amdgpu_waves_per_eu(2)))
void actp_main(
    const float* __restrict__ tact, const float* __restrict__ act,
    const unsigned short* __restrict__ ws,
    const float* __restrict__ b1v, const float* __restrict__ b2v,
    float* __restrict__ out)
{
  __shared__ unsigned short lds[32768];              // 64KB static
  unsigned short* const h1bufA = lds;                // 32*232 = 7424 ush each
  unsigned short* const h1bufB = lds + 7424;
  unsigned short* const h2bufA = lds + 14848;
  unsigned short* const h2bufB = lds + 22272;
  unsigned short* const x1b    = lds + 29696;        // 32*48
  unsigned short* const tld    = lds + 31232;        // 32*48  (end 32768 ush = 64KB)

  const int tid = threadIdx.x, lane = tid & 63, wid = tid >> 6;
  const int q = wid;                                  // gate-col tile; q==7 idle
  const int l31 = lane & 31, kh = lane >> 5;
  const int jc = q * 32 + l31;                        // output column
  const size_t rowbase = (size_t)blockIdx.x * 32;

  const bf16x8* const B1  = (const bf16x8*)ws;
  const bf16x8* const B2  = B1 + (size_t)FRAG_B2  * 64;
  const bf16x8* const BF1 = B1 + (size_t)FRAG_BF1 * 64;
  const bf16x8* const BF2 = B1 + (size_t)FRAG_BF2 * 64;
  const float* const bb1 = (const float*)(ws + (size_t)NFRAG * 512);
  const float* const bb2 = bb1 + 800;
  const bool vv = jc < 200;

  // zero-init the "old" parity state buffers (h(-1) = 0)
  for (int i = tid; i < 3712; i += 512) {
    ((unsigned int*)h1bufB)[i] = 0u;
    ((unsigned int*)h2bufB)[i] = 0u;
  }

  float c1[16], c2[16], tmp[16];
#pragma unroll
  for (int r = 0; r < 16; ++r) { c1[r] = 0.f; c2[r] = 0.f; }

  for (int s = 0; s < 19; ++s) {
    // ---- stage x1 = tactiles[s] (context steps only; pred steps keep out4) --
    if (s < 10 && tid < 192) {
      const int row = tid / 6, ch = tid % 6;
      const float* src = tact + ((size_t)s * 32768 + rowbase + row) * 48 + ch * 8;
      float4 v0 = *(const float4*)src;
      float4 v1 = *(const float4*)(src + 4);
      bf16x8 u;
      u[0] = (short)f2bf(v0.x); u[1] = (short)f2bf(v0.y);
      u[2] = (short)f2bf(v0.z); u[3] = (short)f2bf(v0.w);
      u[4] = (short)f2bf(v1.x); u[5] = (short)f2bf(v1.y);
      u[6] = (short)f2bf(v1.z); u[7] = (short)f2bf(v1.w);
      *(bf16x8*)(x1b + row * 48 + ch * 8) = u;
    }
    // ---- stage tiled(act=actions[s+1], state=actions[0]) -------------------
    if (tid < 64) {
      const int row = tid >> 1, hf = tid & 1;
      const float* pa = act + ((size_t)(s + 1) * 32768 + rowbase + row) * 6;
      const float* ps = act + (rowbase + row) * 6;
      float a6[6], s6[6];
#pragma unroll
      for (int j = 0; j < 6; ++j) { a6[j] = pa[j]; s6[j] = ps[j]; }
#pragma unroll
      for (int k = 0; k < 3; ++k) {
        bf16x8 w;
#pragma unroll
        for (int j = 0; j < 8; ++j) {
          const int c = k * 8 + j;          // local col 0..23; global parity = (c/6)&1
          const int b6 = c / 6, jj = c % 6;
          w[j] = (short)f2bf((b6 & 1) ? s6[jj] : a6[jj]);
        }
        *(bf16x8*)(tld + row * 48 + hf * 24 + k * 8) = w;
      }
    }
    __syncthreads();

    const int P = s & 1;
    unsigned short* const h1n = P ? h1bufB : h1bufA;
    unsigned short* const h1o = P ? h1bufA : h1bufB;
    unsigned short* const h2n = P ? h2bufB : h2bufA;
    unsigned short* const h2o = P ? h2bufA : h2bufB;

    // ================= LSTM1: z = [x1 | h1_old] @ W^T + bb1 =================
    // 4 single-gate passes, order f -> i -> g -> o (minimal carried state).
    if (q < 7) {
      {  // f: c1 *= sig(f)
        f32x16 z = gemm1g<16, 3, 16>(x1b, 48, h1o, 232, h1o, 232,
                                     B1 + (size_t)(112 + q * 16) * 64, lane);
        const float bf = vv ? bb1[200 + jc] : 0.f;
#pragma unroll
        for (int r = 0; r < 16; ++r) c1[r] *= sigf(z[r] + bf);
      }
      {  // i: tmp = sig(i)
        f32x16 z = gemm1g<16, 3, 16>(x1b, 48, h1o, 232, h1o, 232,
                                     B1 + (size_t)(q * 16) * 64, lane);
        const float bi = vv ? bb1[jc] : 0.f;
#pragma unroll
        for (int r = 0; r < 16; ++r) tmp[r] = sigf(z[r] + bi);
      }
      {  // g: c1 += tmp * tanh(g)
        f32x16 z = gemm1g<16, 3, 16>(x1b, 48, h1o, 232, h1o, 232,
                                     B1 + (size_t)(224 + q * 16) * 64, lane);
        const float bg = vv ? bb1[400 + jc] : 0.f;
#pragma unroll
        for (int r = 0; r < 16; ++r) c1[r] += tmp[r] * tanh_f(z[r] + bg);
      }
      {  // o: h1 = sig(o) * tanh(c1)
        f32x16 z = gemm1g<16, 3, 16>(x1b, 48, h1o, 232, h1o, 232,
                                     B1 + (size_t)(336 + q * 16) * 64, lane);
        const float bo = vv ? bb1[600 + jc] : 0.f;
#pragma unroll
        for (int r = 0; r < 16; ++r) {
          const int row = 4 * kh + 8 * (r >> 2) + (r & 3);
          h1n[row * 232 + jc] = f2bf(sigf(z[r] + bo) * tanh_f(c1[r]));
        }
      }
    }
    __syncthreads();

    // ============ LSTM2: z = [h1_new | tiled | h2_old] @ W^T + bb2 ==========
    if (q < 7) {
      {  // f
        f32x16 z = gemm1g<29, 13, 16>(h1n, 232, tld, 48, h2o, 232,
                                      B2 + (size_t)(203 + q * 29) * 64, lane);
        const float bf = vv ? bb2[200 + jc] : 0.f;
#pragma unroll
        for (int r = 0; r < 16; ++r) c2[r] *= sigf(z[r] + bf);
      }
      {  // i
        f32x16 z = gemm1g<29, 13, 16>(h1n, 232, tld, 48, h2o, 232,
                                      B2 + (size_t)(q * 29) * 64, lane);
        const float bi = vv ? bb2[jc] : 0.f;
#pragma unroll
        for (int r = 0; r < 16; ++r) tmp[r] = sigf(z[r] + bi);
      }
      {  // g
        f32x16 z = gemm1g<29, 13, 16>(h1n, 232, tld, 48, h2o, 232,
                                      B2 + (size_t)(406 + q * 29) * 64, lane);
        const float bg = vv ? bb2[400 + jc] : 0.f;
#pragma unroll
        for (int r = 0; r < 16; ++r) c2[r] += tmp[r] * tanh_f(z[r] + bg);
      }
      {  // o
        f32x16 z = gemm1g<29, 13, 16>(h1n, 232, tld, 48, h2o, 232,
                                      B2 + (size_t)(609 + q * 29) * 64, lane);
        const float bo = vv ? bb2[600 + jc] : 0.f;
#pragma unroll
        for (int r = 0; r < 16; ++r) {
          const int row = 4 * kh + 8 * (r >> 2) + (r & 3);
          h2n[row * 232 + jc] = f2bf(sigf(z[r] + bo) * tanh_f(c2[r]));
        }
      }
    }
    __syncthreads();

    // ================= FC1 / FC2 (only for steps that emit output) ==========
    if (s >= 9) {
      unsigned short* const o3 = h1o;   // alias dead h1-old buffer, stride 232
      if (wid < 7) {
        f32x16 a = gemm1g<16, 13, 16>(h2n, 232, x1b, 48, x1b, 48,
                                      BF1 + (size_t)wid * 16 * 64, lane);
        const float br = vv ? b1v[jc] : 0.f;
#pragma unroll
        for (int r = 0; r < 16; ++r) {
          const int row = 4 * kh + 8 * (r >> 2) + (r & 3);
          o3[row * 232 + jc] = f2bf(tanh_f(a[r] + br));
        }
      }
      __syncthreads();
      if (wid < 2) {
        f32x16 a = gemm1g<13, 13, 13>(o3, 232, o3, 232, o3, 232,
                                      BF2 + (size_t)wid * 13 * 64, lane);
        if (jc < 48) {
          const float br = b2v[jc];
#pragma unroll
          for (int r = 0; r < 16; ++r) {
            const int row = 4 * kh + 8 * (r >> 2) + (r & 3);
            const float v = tanh_f(a[r] + br);
            out[((size_t)(s - 9) * 32768 + rowbase + row) * 48 + jc] = v;
            x1b[row * 48 + jc] = f2bf(v);    // out4 -> x1 for next (pred) step
          }
        }
      }
      __syncthreads();
    }
  }
}

// ---------------------------------------------------------------------------
extern "C" void kernel_launch(void* const* d_in, const int* in_sizes, int n_in,
                              void* d_out, int out_size, void* d_ws, size_t ws_size,
                              hipStream_t stream) {
  const float* tactp = (const float*)d_in[0];
  const float* actp  = (const float*)d_in[1];
  const float* Wih1  = (const float*)d_in[2];
  const float* Whh1  = (const float*)d_in[3];
  const float* bih1  = (const float*)d_in[4];
  const float* bhh1  = (const float*)d_in[5];
  const float* Wih2  = (const float*)d_in[6];
  const float* Whh2  = (const float*)d_in[7];
  const float* bih2  = (const float*)d_in[8];
  const float* bhh2  = (const float*)d_in[9];
  const float* W1    = (const float*)d_in[10];
  const float* b1    = (const float*)d_in[11];
  const float* W2    = (const float*)d_in[12];
  const float* b2    = (const float*)d_in[13];
  unsigned short* ws = (unsigned short*)d_ws;
  float* outp = (float*)d_out;

  actp_prep<<<NFRAG + 25, 64, 0, stream>>>(Wih1, Whh1, bih1, bhh1,
                                           Wih2, Whh2, bih2, bhh2, W1, W2, ws);
  actp_main<<<1024, 512, 0, stream>>>(tactp, actp, ws, b1, b2, outp);
}

// Round 4
// 1712.216 us; speedup vs baseline: 3.8424x; 3.8424x over previous
//
#include <hip/hip_runtime.h>

// ============================================================================
// ACTP two-layer LSTM rollout, persistent-kernel bf16-MFMA implementation.
//
// R9 change: revert to R7 (best, 4224us) + scalarize the wave-uniform
// B-fragment stream bases with readfirstlane.
//   Evidence: R8's register diet INCREASED scratch (WRITE 690->784MB,
//   FETCH 5.12->5.84GB) and regressed 4224->6579us -> marginal VGPR
//   pressure is not the spill driver. R7 spill arithmetic: stores 17
//   dwords/thread-step (one 16-dword block written once per step),
//   reloads ~125 dwords/thread-step (= 16 dwords x 8 gemm passes):
//   a pointer-block signature. The B pointers derive from q=wid
//   (threadIdx-derived) -> divergence analysis marks them divergent ->
//   8 pointers live as 16 per-lane VGPRs -> spilled, stored once/step,
//   reloaded every pass. Scratch footprint 64B x 512thr x 128blk/XCD
//   ~= 4MB = L2 size -> thrashes the 1.43MB weight set out of L2,
//   which is why FETCH ~5GB regardless of nominal live set.
//   Fix: q is uniform WITHIN a wave -> readfirstlane(frag_offset) is
//   exact and forces SGPR; B address becomes SGPR base + 32-bit lane
//   offset (canonical global_load_dwordx4 v, v_off, s[base] form).
//
// Structure (= R7):
//  - 1024 blocks x 512 threads (8 waves), 32 batch rows/block, 19 steps.
//  - Wave q=wid: gate-col-tile jt=q (q==7 idle in LSTM gemms). 4 single-gate
//    passes per cell (i -> g -> f -> o, ig[16] carried), one f32x16 AGPR
//    accumulator each; a[4]/b[8] prefetch; biases hoisted.
//  - h1/h2 double-buffered in LDS bf16 (32 rows x stride 232), 64KB static.
//    fc1 "out3" aliases dead h1-old.
//  - Weights pre-converted to bf16 fragment-major (frag = 64 lanes x 16B,
//    coalesced 1KB loads), N padded 200->224 (7 jt of 32), K chunks of 16.
//  - fc1/fc2 skipped for context steps 0..8 (outputs unused).
// MFMA v_mfma_f32_32x32x16_bf16 layouts (per cdna4_isa.md):
//   A: m=lane&31, k=8*(lane>>5)+i ; B: n=lane&31, k=8*(lane>>5)+i
//   C/D: col=lane&31, row=(r&3)+8*(r>>2)+4*(lane>>5)
// ============================================================================

typedef short bf16x8 __attribute__((ext_vector_type(8)));
typedef float f32x16 __attribute__((ext_vector_type(16)));

#define NFRAG    1398
#define FRAG_B2  448     // lstm1: 4*7*16 frags
#define FRAG_BF1 1260    // lstm2: 4*7*29 frags
#define FRAG_BF2 1372    // fc1:   7*16 frags ; fc2: 2*13 frags

__device__ __forceinline__ unsigned short f2bf(float f) {
  unsigned int x = __float_as_uint(f);
  x += 0x7fffu + ((x >> 16) & 1u);          // RNE; inputs are finite
  return (unsigned short)(x >> 16);
}
__device__ __forceinline__ float sigf(float x) {
  return __builtin_amdgcn_rcpf(1.f + __expf(-x));   // exp(inf)->inf->rcp->0: safe
}
__device__ __forceinline__ float tanh_f(float x) {
  float e = __expf(2.f * fabsf(x));                 // e>=1, inf handled (t->1)
  float t = 1.f - 2.f * __builtin_amdgcn_rcpf(e + 1.f);
  return copysignf(t, x);
}

// Force a wave-uniform fragment index into an SGPR and build the stream base.
// frag is uniform within the wave (derived from wid), so readfirstlane is
// exact; the resulting pointer is SGPR-held, not a per-lane VGPR pair.
__device__ __forceinline__ const bf16x8* uni_frag(
    const unsigned short* __restrict__ ws, int frag) {
  const int f = __builtin_amdgcn_readfirstlane(frag);
  return (const bf16x8*)(ws + (size_t)f * 512);     // 512 ushort = 1KB/frag
}

// ---------------------------------------------------------------------------
// Prep: fp32 weights -> bf16 fragment-major in d_ws; biases bb = bih + bhh.
// ---------------------------------------------------------------------------
__global__ void actp_prep(
    const float* __restrict__ Wih1, const float* __restrict__ Whh1,
    const float* __restrict__ bih1, const float* __restrict__ bhh1,
    const float* __restrict__ Wih2, const float* __restrict__ Whh2,
    const float* __restrict__ bih2, const float* __restrict__ bhh2,
    const float* __restrict__ W1,   const float* __restrict__ W2,
    unsigned short* __restrict__ ws)
{
  const int bid = blockIdx.x, l = threadIdx.x;
  if (bid >= NFRAG) {                      // bias blocks
    const int idx = (bid - NFRAG) * 64 + l;
    float* bb = (float*)(ws + (size_t)NFRAG * 512);   // bytes NFRAG*1024
    if (idx < 800)        bb[idx] = bih1[idx] + bhh1[idx];
    else if (idx < 1600)  bb[idx] = bih2[idx - 800] + bhh2[idx - 800];
    return;
  }
  const int ncol = l & 31;
  const int kb   = (l >> 5) * 8;
  float v[8];
  if (bid < FRAG_B2) {                     // lstm1: K = [x1(48) | h1(208 pad)]
    int t = bid; const int g = t / 112; t -= g * 112;
    const int jt = t / 16, kc = t % 16;
    const int n = jt * 32 + ncol, row = g * 200 + n;
#pragma unroll
    for (int i = 0; i < 8; ++i) {
      const int k = kc * 16 + kb + i; float val = 0.f;
      if (n < 200) {
        if (kc < 3) val = Wih1[row * 48 + k];
        else { const int kk = k - 48; if (kk < 200) val = Whh1[row * 200 + kk]; }
      }
      v[i] = val;
    }
  } else if (bid < FRAG_BF1) {             // lstm2: K = [h1 208 | tiled 48 | h2 208]
    int t = bid - FRAG_B2; const int g = t / 203; t -= g * 203;
    const int jt = t / 29, kc = t % 29;
    const int n = jt * 32 + ncol, row = g * 200 + n;
#pragma unroll
    for (int i = 0; i < 8; ++i) {
      const int k = kc * 16 + kb + i; float val = 0.f;
      if (n < 200) {
        if (kc < 13)      { if (k < 200) val = Wih2[row * 248 + k]; }
        else if (kc < 16) { val = Wih2[row * 248 + 200 + (k - 208)]; }
        else { const int kk = k - 256; if (kk < 200) val = Whh2[row * 200 + kk]; }
      }
      v[i] = val;
    }
  } else if (bid < FRAG_BF2) {             // fc1: K = [h2 208 | x1 48]
    int t = bid - FRAG_BF1; const int jt = t / 16, kc = t % 16;
    const int n = jt * 32 + ncol;
#pragma unroll
    for (int i = 0; i < 8; ++i) {
      const int k = kc * 16 + kb + i; float val = 0.f;
      if (n < 200) {
        if (kc < 13) { if (k < 200) val = W1[n * 248 + k]; }
        else         val = W1[n * 248 + 200 + (k - 208)];
      }
      v[i] = val;
    }
  } else {                                 // fc2: K = out3(208 pad), N 48->64
    int t = bid - FRAG_BF2; const int jt = t / 13, kc = t % 13;
    const int n = jt * 32 + ncol;
#pragma unroll
    for (int i = 0; i < 8; ++i) {
      const int k = kc * 16 + kb + i; float val = 0.f;
      if (n < 48 && k < 200) val = W2[n * 200 + k];
      v[i] = val;
    }
  }
  bf16x8 o;
#pragma unroll
  for (int i = 0; i < 8; ++i) o[i] = (short)f2bf(v[i]);
  ((bf16x8*)ws)[(size_t)bid * 64 + l] = o;
}

// ---------------------------------------------------------------------------
// Single-gate GEMM. A from LDS (up to 3 segments), B from global
// fragment-major (SGPR-uniform base). ONE f32x16 accumulator (AGPR).
// A 4-deep, B 8-deep prefetch; all rotating indices compile-time.
// ---------------------------------------------------------------------------
template<int KC, int C1, int C2>
__device__ __forceinline__ f32x16 gemm1g(
    const unsigned short* __restrict__ A1, int S1,
    const unsigned short* __restrict__ A2, int S2,
    const unsigned short* __restrict__ A3, int S3,
    const bf16x8* __restrict__ B, int lane)
{
  const int r32 = lane & 31, ao = (lane >> 5) * 8;
#define APTR(kc) ((kc) < C1 ? (A1 + r32 * S1 + (kc) * 16 + ao) \
               : ((kc) < C2 ? (A2 + r32 * S2 + ((kc) - C1) * 16 + ao) \
                            : (A3 + r32 * S3 + ((kc) - C2) * 16 + ao)))
  f32x16 acc;
#pragma unroll
  for (int r = 0; r < 16; ++r) acc[r] = 0.f;
  bf16x8 a[4];
#pragma unroll
  for (int p = 0; p < 4 && p < KC; ++p) a[p] = *(const bf16x8*)APTR(p);
  bf16x8 b[8];
#pragma unroll
  for (int p = 0; p < 8 && p < KC; ++p) b[p] = B[(size_t)p * 64 + lane];
#pragma unroll
  for (int kc = 0; kc < KC; ++kc) {
    acc = __builtin_amdgcn_mfma_f32_32x32x16_bf16(a[kc & 3], b[kc & 7], acc, 0, 0, 0);
    if (kc + 4 < KC) a[kc & 3] = *(const bf16x8*)APTR(kc + 4);
    if (kc + 8 < KC) b[kc & 7] = B[(size_t)(kc + 8) * 64 + lane];
  }
#undef APTR
  return acc;
}

// ---------------------------------------------------------------------------
// Main persistent kernel: 1024 blocks x 512 threads (8 waves), 32 batch rows
// per block. Static 64KB LDS; waves_per_eu(2).
// ---------------------------------------------------------------------------
__global__ __launch_bounds__(512)
__attribute__((amdgpu_waves_per_eu(2)))
void actp_main(
    const float* __restrict__ tact, const float* __restrict__ act,
    const unsigned short* __restrict__ ws,
    const float* __restrict__ b1v, const float* __restrict__ b2v,
    float* __restrict__ out)
{
  __shared__ unsigned short lds[32768];              // 64KB static
  unsigned short* const h1bufA = lds;                // 32*232 = 7424 ush each
  unsigned short* const h1bufB = lds + 7424;
  unsigned short* const h2bufA = lds + 14848;
  unsigned short* const h2bufB = lds + 22272;
  unsigned short* const x1b    = lds + 29696;        // 32*48
  unsigned short* const tld    = lds + 31232;        // 32*48  (end 32768 ush = 64KB)

  const int tid = threadIdx.x, lane = tid & 63, wid = tid >> 6;
  const int q = wid;                                  // gate-col tile; q==7 idle
  const int l31 = lane & 31, kh = lane >> 5;
  const int jc = q * 32 + l31;                        // output column
  const size_t rowbase = (size_t)blockIdx.x * 32;

  const float* const bb1 = (const float*)(ws + (size_t)NFRAG * 512);
  const float* const bb2 = bb1 + 800;

  // zero-init the "old" parity state buffers (h(-1) = 0)
  for (int i = tid; i < 3712; i += 512) {
    ((unsigned int*)h1bufB)[i] = 0u;
    ((unsigned int*)h2bufB)[i] = 0u;
  }

  // ---- hoist all biases out of the step loop (10 regs, step-invariant) ----
  float bi1 = 0.f, bf1 = 0.f, bg1 = 0.f, bo1 = 0.f;
  float bi2 = 0.f, bf2 = 0.f, bg2 = 0.f, bo2 = 0.f;
  float b1r = 0.f, b2r = 0.f;
  if (jc < 200) {
    bi1 = bb1[jc]; bf1 = bb1[200 + jc]; bg1 = bb1[400 + jc]; bo1 = bb1[600 + jc];
    bi2 = bb2[jc]; bf2 = bb2[200 + jc]; bg2 = bb2[400 + jc]; bo2 = bb2[600 + jc];
    b1r = b1v[jc];
    if (jc < 48) b2r = b2v[jc];
  }

  float c1[16], c2[16], ig[16];
#pragma unroll
  for (int r = 0; r < 16; ++r) { c1[r] = 0.f; c2[r] = 0.f; }

  for (int s = 0; s < 19; ++s) {
    // ---- stage x1 = tactiles[s] (context steps only; pred steps keep out4) --
    if (s < 10 && tid < 192) {
      const int row = tid / 6, ch = tid % 6;
      const float* src = tact + ((size_t)s * 32768 + rowbase + row) * 48 + ch * 8;
      float4 v0 = *(const float4*)src;
      float4 v1 = *(const float4*)(src + 4);
      bf16x8 u;
      u[0] = (short)f2bf(v0.x); u[1] = (short)f2bf(v0.y);
      u[2] = (short)f2bf(v0.z); u[3] = (short)f2bf(v0.w);
      u[4] = (short)f2bf(v1.x); u[5] = (short)f2bf(v1.y);
      u[6] = (short)f2bf(v1.z); u[7] = (short)f2bf(v1.w);
      *(bf16x8*)(x1b + row * 48 + ch * 8) = u;
    }
    // ---- stage tiled(act=actions[s+1], state=actions[0]) -------------------
    if (tid < 64) {
      const int row = tid >> 1, hf = tid & 1;
      const float* pa = act + ((size_t)(s + 1) * 32768 + rowbase + row) * 6;
      const float* ps = act + (rowbase + row) * 6;
      float a6[6], s6[6];
#pragma unroll
      for (int j = 0; j < 6; ++j) { a6[j] = pa[j]; s6[j] = ps[j]; }
#pragma unroll
      for (int k = 0; k < 3; ++k) {
        bf16x8 w;
#pragma unroll
        for (int j = 0; j < 8; ++j) {
          const int c = k * 8 + j;          // local col 0..23; global parity = (c/6)&1
          const int b6 = c / 6, jj = c % 6;
          w[j] = (short)f2bf((b6 & 1) ? s6[jj] : a6[jj]);
        }
        *(bf16x8*)(tld + row * 48 + hf * 24 + k * 8) = w;
      }
    }
    __syncthreads();

    const int P = s & 1;
    unsigned short* const h1n = P ? h1bufB : h1bufA;
    unsigned short* const h1o = P ? h1bufA : h1bufB;
    unsigned short* const h2n = P ? h2bufB : h2bufA;
    unsigned short* const h2o = P ? h2bufA : h2bufB;

    // ================= LSTM1: z = [x1 | h1_old] @ W^T + bb1 =================
    // 4 single-gate passes: i -> g -> f -> o. One AGPR accumulator each.
    // B stream bases forced into SGPRs via uni_frag (wave-uniform).
    if (q < 7) {
      {
        f32x16 z = gemm1g<16, 3, 16>(x1b, 48, h1o, 232, h1o, 232,
                                     uni_frag(ws, q * 16), lane);
#pragma unroll
        for (int r = 0; r < 16; ++r) ig[r] = sigf(z[r] + bi1);
      }
      {
        f32x16 z = gemm1g<16, 3, 16>(x1b, 48, h1o, 232, h1o, 232,
                                     uni_frag(ws, 224 + q * 16), lane);
#pragma unroll
        for (int r = 0; r < 16; ++r) ig[r] *= tanh_f(z[r] + bg1);
      }
      {
        f32x16 z = gemm1g<16, 3, 16>(x1b, 48, h1o, 232, h1o, 232,
                                     uni_frag(ws, 112 + q * 16), lane);
#pragma unroll
        for (int r = 0; r < 16; ++r) c1[r] = sigf(z[r] + bf1) * c1[r] + ig[r];
      }
      {
        f32x16 z = gemm1g<16, 3, 16>(x1b, 48, h1o, 232, h1o, 232,
                                     uni_frag(ws, 336 + q * 16), lane);
#pragma unroll
        for (int r = 0; r < 16; ++r) {
          const int row = 4 * kh + 8 * (r >> 2) + (r & 3);
          h1n[row * 232 + jc] = f2bf(sigf(z[r] + bo1) * tanh_f(c1[r]));
        }
      }
    }
    __syncthreads();

    // ============ LSTM2: z = [h1_new | tiled | h2_old] @ W^T + bb2 ==========
    if (q < 7) {
      {
        f32x16 z = gemm1g<29, 13, 16>(h1n, 232, tld, 48, h2o, 232,
                                      uni_frag(ws, FRAG_B2 + q * 29), lane);
#pragma unroll
        for (int r = 0; r < 16; ++r) ig[r] = sigf(z[r] + bi2);
      }
      {
        f32x16 z = gemm1g<29, 13, 16>(h1n, 232, tld, 48, h2o, 232,
                                      uni_frag(ws, FRAG_B2 + 406 + q * 29), lane);
#pragma unroll
        for (int r = 0; r < 16; ++r) ig[r] *= tanh_f(z[r] + bg2);
      }
      {
        f32x16 z = gemm1g<29, 13, 16>(h1n, 232, tld, 48, h2o, 232,
                                      uni_frag(ws, FRAG_B2 + 203 + q * 29), lane);
#pragma unroll
        for (int r = 0; r < 16; ++r) c2[r] = sigf(z[r] + bf2) * c2[r] + ig[r];
      }
      {
        f32x16 z = gemm1g<29, 13, 16>(h1n, 232, tld, 48, h2o, 232,
                                      uni_frag(ws, FRAG_B2 + 609 + q * 29), lane);
#pragma unroll
        for (int r = 0; r < 16; ++r) {
          const int row = 4 * kh + 8 * (r >> 2) + (r & 3);
          h2n[row * 232 + jc] = f2bf(sigf(z[r] + bo2) * tanh_f(c2[r]));
        }
      }
    }
    __syncthreads();

    // ================= FC1 / FC2 (only for steps that emit output) ==========
    if (s >= 9) {
      unsigned short* const o3 = h1o;   // alias dead h1-old buffer, stride 232
      if (wid < 7) {
        f32x16 a = gemm1g<16, 13, 16>(h2n, 232, x1b, 48, x1b, 48,
                                      uni_frag(ws, FRAG_BF1 + wid * 16), lane);
#pragma unroll
        for (int r = 0; r < 16; ++r) {
          const int row = 4 * kh + 8 * (r >> 2) + (r & 3);
          o3[row * 232 + jc] = f2bf(tanh_f(a[r] + b1r));
        }
      }
      __syncthreads();
      if (wid < 2) {
        f32x16 a = gemm1g<13, 13, 13>(o3, 232, o3, 232, o3, 232,
                                      uni_frag(ws, FRAG_BF2 + wid * 13), lane);
        if (jc < 48) {
#pragma unroll
          for (int r = 0; r < 16; ++r) {
            const int row = 4 * kh + 8 * (r >> 2) + (r & 3);
            const float v = tanh_f(a[r] + b2r);
            out[((size_t)(s - 9) * 32768 + rowbase + row) * 48 + jc] = v;
            x1b[row * 48 + jc] = f2bf(v);    // out4 -> x1 for next (pred) step
          }
        }
      }
      __syncthreads();
    }
  }
}

// ---------------------------------------------------------------------------
extern "C" void kernel_launch(void* const* d_in, const int* in_sizes, int n_in,
                              void* d_out, int out_size, void* d_ws, size_t ws_size,
                              hipStream_t stream) {
  const float* tactp = (const float*)d_in[0];
  const float* actp  = (const float*)d_in[1];
  const float* Wih1  = (const float*)d_in[2];
  const float* Whh1  = (const float*)d_in[3];
  const float* bih1  = (const float*)d_in[4];
  const float* bhh1  = (const float*)d_in[5];
  const float* Wih2  = (const float*)d_in[6];
  const float* Whh2  = (const float*)d_in[7];
  const float* bih2  = (const float*)d_in[8];
  const float* bhh2  = (const float*)d_in[9];
  const float* W1    = (const float*)d_in[10];
  const float* b1    = (const float*)d_in[11];
  const float* W2    = (const float*)d_in[12];
  const float* b2    = (const float*)d_in[13];
  unsigned short* ws = (unsigned short*)d_ws;
  float* outp = (float*)d_out;

  actp_prep<<<NFRAG + 25, 64, 0, stream>>>(Wih1, Whh1, bih1, bhh1,
                                           Wih2, Whh2, bih2, bhh2, W1, W2, ws);
  actp_main<<<1024, 512, 0, stream>>>(tactp, actp, ws, b1, b2, outp);
}

// Round 6
// 1537.152 us; speedup vs baseline: 4.2800x; 1.1139x over previous
//
#include <hip/hip_runtime.h>

// ============================================================================
// ACTP two-layer LSTM rollout, persistent-kernel bf16-MFMA implementation.
//
// R11 = R10 resubmitted verbatim (R10's bench was an infrastructure failure:
// "MI355X container failed twice" — kernel never executed).
//
// R10 change: drive scratch to ZERO on top of R9's scalarized B pointers.
//   Evidence (R9 counters): dur 1712us, FETCH 96MB (pointer-reload storm
//   gone -> theory confirmed), but WRITE 924MB = ~860MB scratch stores
//   (~21 dw/thread-step): worst-pass live set ~130 > 128 budget, compiler
//   parks a 16-reg block (idle cell's c state) every step. Occupancy 23%
//   = 1 block/CU despite LDS and VGPR both permitting 2 -> suspect the
//   nonzero private segment limits co-residency.
//   Fixes (register diet at pass boundaries ONLY; prefetch + scalar
//   pointers untouched -- R8's confound is resolved):
//    1. Gate order f -> i -> g -> o: c *= sig(f) in place (no temp);
//       tmp = sig(i) lives across one boundary; c += tmp*tanh(g); o last.
//    2. Biases un-hoisted: per-pass dword load issued BEFORE the gemm,
//       latency hidden under 16-29 MFMAs. -10 loop-scope regs.
//   Worst-pass nominal: c1 16 + c2 16 + tmp 16 + acc 16 + b[8] 32 +
//   a[4] 16 + bias 1 + addr ~8 = ~121 <= 128.
//   Readout: WRITE_SIZE -> ~70MB. If occupancy then doubles, scratch was
//   the co-residency limiter; if not, R12 targets L2 weight traffic
//   (27.8GB @ 16.3TB/s = 47% of L2 ceiling) via LDS-staged B sharing.
//
// Structure:
//  - 1024 blocks x 512 threads (8 waves), 32 batch rows/block, 19 steps.
//  - Wave q=wid: gate-col-tile jt=q (q==7 idle in LSTM gemms). 4 single-gate
//    passes per cell (f->i->g->o), one f32x16 AGPR accumulator each;
//    a[4]/b[8] prefetch; B stream bases scalarized via readfirstlane.
//  - h1/h2 double-buffered in LDS bf16 (32 rows x stride 232), 64KB static.
//    fc1 "out3" aliases dead h1-old.
//  - Weights pre-converted to bf16 fragment-major (frag = 64 lanes x 16B,
//    coalesced 1KB loads), N padded 200->224 (7 jt of 32), K chunks of 16.
//  - fc1/fc2 skipped for context steps 0..8 (outputs unused).
// MFMA v_mfma_f32_32x32x16_bf16 layouts (per cdna4_isa.md):
//   A: m=lane&31, k=8*(lane>>5)+i ; B: n=lane&31, k=8*(lane>>5)+i
//   C/D: col=lane&31, row=(r&3)+8*(r>>2)+4*(lane>>5)
// ============================================================================

typedef short bf16x8 __attribute__((ext_vector_type(8)));
typedef float f32x16 __attribute__((ext_vector_type(16)));

#define NFRAG    1398
#define FRAG_B2  448     // lstm1: 4*7*16 frags
#define FRAG_BF1 1260    // lstm2: 4*7*29 frags
#define FRAG_BF2 1372    // fc1:   7*16 frags ; fc2: 2*13 frags

__device__ __forceinline__ unsigned short f2bf(float f) {
  unsigned int x = __float_as_uint(f);
  x += 0x7fffu + ((x >> 16) & 1u);          // RNE; inputs are finite
  return (unsigned short)(x >> 16);
}
__device__ __forceinline__ float sigf(float x) {
  return __builtin_amdgcn_rcpf(1.f + __expf(-x));   // exp(inf)->inf->rcp->0: safe
}
__device__ __forceinline__ float tanh_f(float x) {
  float e = __expf(2.f * fabsf(x));                 // e>=1, inf handled (t->1)
  float t = 1.f - 2.f * __builtin_amdgcn_rcpf(e + 1.f);
  return copysignf(t, x);
}

// Force a wave-uniform fragment index into an SGPR and build the stream base.
// frag is uniform within the wave (derived from wid), so readfirstlane is
// exact; the resulting pointer is SGPR-held, not a per-lane VGPR pair.
__device__ __forceinline__ const bf16x8* uni_frag(
    const unsigned short* __restrict__ ws, int frag) {
  const int f = __builtin_amdgcn_readfirstlane(frag);
  return (const bf16x8*)(ws + (size_t)f * 512);     // 512 ushort = 1KB/frag
}

// ---------------------------------------------------------------------------
// Prep: fp32 weights -> bf16 fragment-major in d_ws; biases bb = bih + bhh.
// ---------------------------------------------------------------------------
__global__ void actp_prep(
    const float* __restrict__ Wih1, const float* __restrict__ Whh1,
    const float* __restrict__ bih1, const float* __restrict__ bhh1,
    const float* __restrict__ Wih2, const float* __restrict__ Whh2,
    const float* __restrict__ bih2, const float* __restrict__ bhh2,
    const float* __restrict__ W1,   const float* __restrict__ W2,
    unsigned short* __restrict__ ws)
{
  const int bid = blockIdx.x, l = threadIdx.x;
  if (bid >= NFRAG) {                      // bias blocks
    const int idx = (bid - NFRAG) * 64 + l;
    float* bb = (float*)(ws + (size_t)NFRAG * 512);   // bytes NFRAG*1024
    if (idx < 800)        bb[idx] = bih1[idx] + bhh1[idx];
    else if (idx < 1600)  bb[idx] = bih2[idx - 800] + bhh2[idx - 800];
    return;
  }
  const int ncol = l & 31;
  const int kb   = (l >> 5) * 8;
  float v[8];
  if (bid < FRAG_B2) {                     // lstm1: K = [x1(48) | h1(208 pad)]
    int t = bid; const int g = t / 112; t -= g * 112;
    const int jt = t / 16, kc = t % 16;
    const int n = jt * 32 + ncol, row = g * 200 + n;
#pragma unroll
    for (int i = 0; i < 8; ++i) {
      const int k = kc * 16 + kb + i; float val = 0.f;
      if (n < 200) {
        if (kc < 3) val = Wih1[row * 48 + k];
        else { const int kk = k - 48; if (kk < 200) val = Whh1[row * 200 + kk]; }
      }
      v[i] = val;
    }
  } else if (bid < FRAG_BF1) {             // lstm2: K = [h1 208 | tiled 48 | h2 208]
    int t = bid - FRAG_B2; const int g = t / 203; t -= g * 203;
    const int jt = t / 29, kc = t % 29;
    const int n = jt * 32 + ncol, row = g * 200 + n;
#pragma unroll
    for (int i = 0; i < 8; ++i) {
      const int k = kc * 16 + kb + i; float val = 0.f;
      if (n < 200) {
        if (kc < 13)      { if (k < 200) val = Wih2[row * 248 + k]; }
        else if (kc < 16) { val = Wih2[row * 248 + 200 + (k - 208)]; }
        else { const int kk = k - 256; if (kk < 200) val = Whh2[row * 200 + kk]; }
      }
      v[i] = val;
    }
  } else if (bid < FRAG_BF2) {             // fc1: K = [h2 208 | x1 48]
    int t = bid - FRAG_BF1; const int jt = t / 16, kc = t % 16;
    const int n = jt * 32 + ncol;
#pragma unroll
    for (int i = 0; i < 8; ++i) {
      const int k = kc * 16 + kb + i; float val = 0.f;
      if (n < 200) {
        if (kc < 13) { if (k < 200) val = W1[n * 248 + k]; }
        else         val = W1[n * 248 + 200 + (k - 208)];
      }
      v[i] = val;
    }
  } else {                                 // fc2: K = out3(208 pad), N 48->64
    int t = bid - FRAG_BF2; const int jt = t / 13, kc = t % 13;
    const int n = jt * 32 + ncol;
#pragma unroll
    for (int i = 0; i < 8; ++i) {
      const int k = kc * 16 + kb + i; float val = 0.f;
      if (n < 48 && k < 200) val = W2[n * 200 + k];
      v[i] = val;
    }
  }
  bf16x8 o;
#pragma unroll
  for (int i = 0; i < 8; ++i) o[i] = (short)f2bf(v[i]);
  ((bf16x8*)ws)[(size_t)bid * 64 + l] = o;
}

// ---------------------------------------------------------------------------
// Single-gate GEMM. A from LDS (up to 3 segments), B from global
// fragment-major (SGPR-uniform base). ONE f32x16 accumulator (AGPR).
// A 4-deep, B 8-deep prefetch; all rotating indices compile-time.
// ---------------------------------------------------------------------------
template<int KC, int C1, int C2>
__device__ __forceinline__ f32x16 gemm1g(
    const unsigned short* __restrict__ A1, int S1,
    const unsigned short* __restrict__ A2, int S2,
    const unsigned short* __restrict__ A3, int S3,
    const bf16x8* __restrict__ B, int lane)
{
  const int r32 = lane & 31, ao = (lane >> 5) * 8;
#define APTR(kc) ((kc) < C1 ? (A1 + r32 * S1 + (kc) * 16 + ao) \
               : ((kc) < C2 ? (A2 + r32 * S2 + ((kc) - C1) * 16 + ao) \
                            : (A3 + r32 * S3 + ((kc) - C2) * 16 + ao)))
  f32x16 acc;
#pragma unroll
  for (int r = 0; r < 16; ++r) acc[r] = 0.f;
  bf16x8 a[4];
#pragma unroll
  for (int p = 0; p < 4 && p < KC; ++p) a[p] = *(const bf16x8*)APTR(p);
  bf16x8 b[8];
#pragma unroll
  for (int p = 0; p < 8 && p < KC; ++p) b[p] = B[(size_t)p * 64 + lane];
#pragma unroll
  for (int kc = 0; kc < KC; ++kc) {
    acc = __builtin_amdgcn_mfma_f32_32x32x16_bf16(a[kc & 3], b[kc & 7], acc, 0, 0, 0);
    if (kc + 4 < KC) a[kc & 3] = *(const bf16x8*)APTR(kc + 4);
    if (kc + 8 < KC) b[kc & 7] = B[(size_t)(kc + 8) * 64 + lane];
  }
#undef APTR
  return acc;
}

// ---------------------------------------------------------------------------
// Main persistent kernel: 1024 blocks x 512 threads (8 waves), 32 batch rows
// per block. Static 64KB LDS; waves_per_eu(2).
// ---------------------------------------------------------------------------
__global__ __launch_bounds__(512)
__attribute__((amdgpu_waves_per_eu(2)))
void actp_main(
    const float* __restrict__ tact, const float* __restrict__ act,
    const unsigned short* __restrict__ ws,
    const float* __restrict__ b1v, const float* __restrict__ b2v,
    float* __restrict__ out)
{
  __shared__ unsigned short lds[32768];              // 64KB static
  unsigned short* const h1bufA = lds;                // 32*232 = 7424 ush each
  unsigned short* const h1bufB = lds + 7424;
  unsigned short* const h2bufA = lds + 14848;
  unsigned short* const h2bufB = lds + 22272;
  unsigned short* const x1b    = lds + 29696;        // 32*48
  unsigned short* const tld    = lds + 31232;        // 32*48  (end 32768 ush = 64KB)

  const int tid = threadIdx.x, lane = tid & 63, wid = tid >> 6;
  const int q = wid;                                  // gate-col tile; q==7 idle
  const int l31 = lane & 31, kh = lane >> 5;
  const int jc = q * 32 + l31;                        // output column
  const size_t rowbase = (size_t)blockIdx.x * 32;

  const float* const bb1 = (const float*)(ws + (size_t)NFRAG * 512);
  const float* const bb2 = bb1 + 800;
  const bool vv = jc < 200;

  // zero-init the "old" parity state buffers (h(-1) = 0)
  for (int i = tid; i < 3712; i += 512) {
    ((unsigned int*)h1bufB)[i] = 0u;
    ((unsigned int*)h2bufB)[i] = 0u;
  }

  float c1[16], c2[16], tmp[16];
#pragma unroll
  for (int r = 0; r < 16; ++r) { c1[r] = 0.f; c2[r] = 0.f; }

  for (int s = 0; s < 19; ++s) {
    // ---- stage x1 = tactiles[s] (context steps only; pred steps keep out4) --
    if (s < 10 && tid < 192) {
      const int row = tid / 6, ch = tid % 6;
      const float* src = tact + ((size_t)s * 32768 + rowbase + row) * 48 + ch * 8;
      float4 v0 = *(const float4*)src;
      float4 v1 = *(const float4*)(src + 4);
      bf16x8 u;
      u[0] = (short)f2bf(v0.x); u[1] = (short)f2bf(v0.y);
      u[2] = (short)f2bf(v0.z); u[3] = (short)f2bf(v0.w);
      u[4] = (short)f2bf(v1.x); u[5] = (short)f2bf(v1.y);
      u[6] = (short)f2bf(v1.z); u[7] = (short)f2bf(v1.w);
      *(bf16x8*)(x1b + row * 48 + ch * 8) = u;
    }
    // ---- stage tiled(act=actions[s+1], state=actions[0]) -------------------
    if (tid < 64) {
      const int row = tid >> 1, hf = tid & 1;
      const float* pa = act + ((size_t)(s + 1) * 32768 + rowbase + row) * 6;
      const float* ps = act + (rowbase + row) * 6;
      float a6[6], s6[6];
#pragma unroll
      for (int j = 0; j < 6; ++j) { a6[j] = pa[j]; s6[j] = ps[j]; }
#pragma unroll
      for (int k = 0; k < 3; ++k) {
        bf16x8 w;
#pragma unroll
        for (int j = 0; j < 8; ++j) {
          const int c = k * 8 + j;          // local col 0..23; global parity = (c/6)&1
          const int b6 = c / 6, jj = c % 6;
          w[j] = (short)f2bf((b6 & 1) ? s6[jj] : a6[jj]);
        }
        *(bf16x8*)(tld + row * 48 + hf * 24 + k * 8) = w;
      }
    }
    __syncthreads();

    const int P = s & 1;
    unsigned short* const h1n = P ? h1bufB : h1bufA;
    unsigned short* const h1o = P ? h1bufA : h1bufB;
    unsigned short* const h2n = P ? h2bufB : h2bufA;
    unsigned short* const h2o = P ? h2bufA : h2bufB;

    // ================= LSTM1: z = [x1 | h1_old] @ W^T + bb1 =================
    // 4 single-gate passes, order f -> i -> g -> o (minimal carried state).
    // B stream bases forced into SGPRs via uni_frag (wave-uniform).
    if (q < 7) {
      {  // f: c1 *= sig(f)
        const float bf = vv ? bb1[200 + jc] : 0.f;
        f32x16 z = gemm1g<16, 3, 16>(x1b, 48, h1o, 232, h1o, 232,
                                     uni_frag(ws, 112 + q * 16), lane);
#pragma unroll
        for (int r = 0; r < 16; ++r) c1[r] *= sigf(z[r] + bf);
      }
      {  // i: tmp = sig(i)
        const float bi = vv ? bb1[jc] : 0.f;
        f32x16 z = gemm1g<16, 3, 16>(x1b, 48, h1o, 232, h1o, 232,
                                     uni_frag(ws, q * 16), lane);
#pragma unroll
        for (int r = 0; r < 16; ++r) tmp[r] = sigf(z[r] + bi);
      }
      {  // g: c1 += tmp * tanh(g)
        const float bg = vv ? bb1[400 + jc] : 0.f;
        f32x16 z = gemm1g<16, 3, 16>(x1b, 48, h1o, 232, h1o, 232,
                                     uni_frag(ws, 224 + q * 16), lane);
#pragma unroll
        for (int r = 0; r < 16; ++r) c1[r] += tmp[r] * tanh_f(z[r] + bg);
      }
      {  // o: h1 = sig(o) * tanh(c1)
        const float bo = vv ? bb1[600 + jc] : 0.f;
        f32x16 z = gemm1g<16, 3, 16>(x1b, 48, h1o, 232, h1o, 232,
                                     uni_frag(ws, 336 + q * 16), lane);
#pragma unroll
        for (int r = 0; r < 16; ++r) {
          const int row = 4 * kh + 8 * (r >> 2) + (r & 3);
          h1n[row * 232 + jc] = f2bf(sigf(z[r] + bo) * tanh_f(c1[r]));
        }
      }
    }
    __syncthreads();

    // ============ LSTM2: z = [h1_new | tiled | h2_old] @ W^T + bb2 ==========
    if (q < 7) {
      {  // f
        const float bf = vv ? bb2[200 + jc] : 0.f;
        f32x16 z = gemm1g<29, 13, 16>(h1n, 232, tld, 48, h2o, 232,
                                      uni_frag(ws, FRAG_B2 + 203 + q * 29), lane);
#pragma unroll
        for (int r = 0; r < 16; ++r) c2[r] *= sigf(z[r] + bf);
      }
      {  // i
        const float bi = vv ? bb2[jc] : 0.f;
        f32x16 z = gemm1g<29, 13, 16>(h1n, 232, tld, 48, h2o, 232,
                                      uni_frag(ws, FRAG_B2 + q * 29), lane);
#pragma unroll
        for (int r = 0; r < 16; ++r) tmp[r] = sigf(z[r] + bi);
      }
      {  // g
        const float bg = vv ? bb2[400 + jc] : 0.f;
        f32x16 z = gemm1g<29, 13, 16>(h1n, 232, tld, 48, h2o, 232,
                                      uni_frag(ws, FRAG_B2 + 406 + q * 29), lane);
#pragma unroll
        for (int r = 0; r < 16; ++r) c2[r] += tmp[r] * tanh_f(z[r] + bg);
      }
      {  // o
        const float bo = vv ? bb2[600 + jc] : 0.f;
        f32x16 z = gemm1g<29, 13, 16>(h1n, 232, tld, 48, h2o, 232,
                                      uni_frag(ws, FRAG_B2 + 609 + q * 29), lane);
#pragma unroll
        for (int r = 0; r < 16; ++r) {
          const int row = 4 * kh + 8 * (r >> 2) + (r & 3);
          h2n[row * 232 + jc] = f2bf(sigf(z[r] + bo) * tanh_f(c2[r]));
        }
      }
    }
    __syncthreads();

    // ================= FC1 / FC2 (only for steps that emit output) ==========
    if (s >= 9) {
      unsigned short* const o3 = h1o;   // alias dead h1-old buffer, stride 232
      if (wid < 7) {
        const float br = vv ? b1v[jc] : 0.f;
        f32x16 a = gemm1g<16, 13, 16>(h2n, 232, x1b, 48, x1b, 48,
                                      uni_frag(ws, FRAG_BF1 + wid * 16), lane);
#pragma unroll
        for (int r = 0; r < 16; ++r) {
          const int row = 4 * kh + 8 * (r >> 2) + (r & 3);
          o3[row * 232 + jc] = f2bf(tanh_f(a[r] + br));
        }
      }
      __syncthreads();
      if (wid < 2) {
        const float br = (jc < 48) ? b2v[jc] : 0.f;
        f32x16 a = gemm1g<13, 13, 13>(o3, 232, o3, 232, o3, 232,
                                      uni_frag(ws, FRAG_BF2 + wid * 13), lane);
        if (jc < 48) {
#pragma unroll
          for (int r = 0; r < 16; ++r) {
            const int row = 4 * kh + 8 * (r >> 2) + (r & 3);
            const float v = tanh_f(a[r] + br);
            out[((size_t)(s - 9) * 32768 + rowbase + row) * 48 + jc] = v;
            x1b[row * 48 + jc] = f2bf(v);    // out4 -> x1 for next (pred) step
          }
        }
      }
      __syncthreads();
    }
  }
}

// ---------------------------------------------------------------------------
extern "C" void kernel_launch(void* const* d_in, const int* in_sizes, int n_in,
                              void* d_out, int out_size, void* d_ws, size_t ws_size,
                              hipStream_t stream) {
  const float* tactp = (const float*)d_in[0];
  const float* actp  = (const float*)d_in[1];
  const float* Wih1  = (const float*)d_in[2];
  const float* Whh1  = (const float*)d_in[3];
  const float* bih1  = (const float*)d_in[4];
  const float* bhh1  = (const float*)d_in[5];
  const float* Wih2  = (const float*)d_in[6];
  const float* Whh2  = (const float*)d_in[7];
  const float* bih2  = (const float*)d_in[8];
  const float* bhh2  = (const float*)d_in[9];
  const float* W1    = (const float*)d_in[10];
  const float* b1    = (const float*)d_in[11];
  const float* W2    = (const float*)d_in[12];
  const float* b2    = (const float*)d_in[13];
  unsigned short* ws = (unsigned short*)d_ws;
  float* outp = (float*)d_out;

  actp_prep<<<NFRAG + 25, 64, 0, stream>>>(Wih1, Whh1, bih1, bhh1,
                                           Wih2, Whh2, bih2, bhh2, W1, W2, ws);
  actp_main<<<1024, 512, 0, stream>>>(tactp, actp, ws, b1, b2, outp);
}